// Round 9
// baseline (7033.482 us; speedup 1.0000x reference)
//
#include <hip/hip_runtime.h>
#include <math.h>

// Sinkhorn OT layer, B=8192, C=256, L=100, LAMBD=1.
//
// U = log_u - ||x_i||^2, V = log_v - ||y_j||^2, G[i][j] = 2*dot(x_i,y_j):
//   U[i] = -LSE_j(G[i][j] + V[j]),  V[j] = -LSE_i(G[i][j] + U[i])
// init V[j] = -||y_j||^2. Final: out[i] = y[argmax_j(G[i][j]+V[j])].
//
// R6 int24 G: 7498. R11 register-resident fused iter: 4930. R13 one-barrier
// window: 4875 (~43 us/iter = 87% of the dense 224MiB BW floor).
// R14: SPARSE Sinkhorn. Entries > tau=80 below the row max contribute
// <= 8192*e^-80 ~ e^-71 relative to any LSE/colsum -- negligible vs the
// int24 noise (1.5e-5) already accepted. Schedule:
//   8 dense iters -> extract per-row candidates (idx u16 + int24 G,
//   KMAX=1024, per-row tau-tightening) -> sparse iters (LDS colsum
//   partials, V gathered from LDS, NO global atomics) with RE-EXTRACTION
//   every 24 iters (drift insurance; V_new ~ -log A_j is memoryless in
//   V_old so transient errors self-heal). Sparse combine FREEZES V_j on
//   exactly-zero colsum (prevents +69-runaway for globally-dropped cols;
//   re-extract restores them). Dense kernels byte-identical to R13.
// Schedule: 8 dense | X | 24 sp | 1 dense | X | 23 sp | 1 dense | X |
//           23 sp | 1 dense | X | 19 sp  = 100 iters, 4 extracts.
// ws: Glo 128 + Ghi 64 + pm 16 + sidx 16 + svlo 16 + svhi 8 = 248 MiB.

#define B 8192
#define C 256
#define RPB 16                     // rows per dense fused block
#define NCH 512                    // dense partial chunks
#define KMAX 1024                  // sparse entries per row (cap)
#define SROWS 32                   // rows per sparse block
#define SNCH (B / SROWS)           // 256 sparse partial chunks

#define QS 65536.0f                // (2*acc) * 32768 == acc * 65536
#define QI 3.0517578125e-5f        // 2^-15

typedef float f32x4 __attribute__((ext_vector_type(4)));
typedef unsigned short u16x8 __attribute__((ext_vector_type(8)));
typedef signed char i8x16 __attribute__((ext_vector_type(16)));
typedef signed char i8x8 __attribute__((ext_vector_type(8)));

__device__ __align__(16) float g_V[B];
__device__ int g_cnt[B];

// ---------------- init: V[j] = -||y_j||^2 ----------------
__global__ __launch_bounds__(256) void init_V(const float* __restrict__ y) {
    int wave = threadIdx.x >> 6;
    int lane = threadIdx.x & 63;
    int row = blockIdx.x * 4 + wave;
    const f32x4* yr = (const f32x4*)(y + (size_t)row * C);
    f32x4 v = yr[lane];
    float s = v.x * v.x + v.y * v.y + v.z * v.z + v.w * v.w;
    #pragma unroll
    for (int off = 32; off; off >>= 1) s += __shfl_down(s, off, 64);
    if (lane == 0) g_V[row] = -s;
}

// ---------------- GEMM: G = 2 * x @ y^T, quantized to int24 (R6 version) ----------------
#define GT 64
#define GKT 64
#define LSTR (GKT + 4)   // 68 floats; float4-aligned offsets

__global__ __launch_bounds__(256) void gemm_G(const float* __restrict__ x,
                                              const float* __restrict__ y,
                                              unsigned short* __restrict__ Glo,
                                              signed char* __restrict__ Ghi) {
    __shared__ float As[GT][LSTR];   // [i][k]
    __shared__ float Bs[GT][LSTR];   // [j][k]
    int bi = blockIdx.y * GT;
    int bj = blockIdx.x * GT;
    int t = threadIdx.x;
    int tx = t & 15, ty = t >> 4;
    float acc[4][4] = {};
    for (int kk = 0; kk < C; kk += GKT) {
        #pragma unroll
        for (int l = 0; l < 4; ++l) {
            int idx = t + l * 256;         // float4 index in tile
            int r = idx >> 4;              // tile row 0..63
            int c4 = idx & 15;             // float4 col 0..15
            *(f32x4*)&As[r][c4 * 4] =
                *(const f32x4*)(x + (size_t)(bi + r) * C + kk + c4 * 4);
            *(f32x4*)&Bs[r][c4 * 4] =
                *(const f32x4*)(y + (size_t)(bj + r) * C + kk + c4 * 4);
        }
        __syncthreads();
        #pragma unroll
        for (int k4 = 0; k4 < GKT / 4; ++k4) {
            f32x4 a[4], b[4];
            #pragma unroll
            for (int ii = 0; ii < 4; ++ii)
                a[ii] = *(const f32x4*)&As[ty * 4 + ii][k4 * 4];
            #pragma unroll
            for (int jj = 0; jj < 4; ++jj)
                b[jj] = *(const f32x4*)&Bs[tx + 16 * jj][k4 * 4];
            #pragma unroll
            for (int ii = 0; ii < 4; ++ii)
                #pragma unroll
                for (int jj = 0; jj < 4; ++jj) {
                    acc[ii][jj] = fmaf(a[ii].x, b[jj].x, acc[ii][jj]);
                    acc[ii][jj] = fmaf(a[ii].y, b[jj].y, acc[ii][jj]);
                    acc[ii][jj] = fmaf(a[ii].z, b[jj].z, acc[ii][jj]);
                    acc[ii][jj] = fmaf(a[ii].w, b[jj].w, acc[ii][jj]);
                }
        }
        __syncthreads();
    }
    #pragma unroll
    for (int ii = 0; ii < 4; ++ii) {
        int gi = bi + ty * 4 + ii;
        #pragma unroll
        for (int jj = 0; jj < 4; ++jj) {
            size_t idx = (size_t)gi * B + bj + tx + 16 * jj;
            float gs = acc[ii][jj] * QS;                       // G * 2^15
            gs = fminf(fmaxf(gs, -8388607.0f), 8388607.0f);    // int24 clamp
            int v = __float2int_rn(gs);
            Glo[idx] = (unsigned short)(v & 0xFFFF);
            Ghi[idx] = (signed char)(v >> 16);
        }
    }
}

// ---------------- dense fused row+col pass (R13, unchanged) ----------------
__global__ __launch_bounds__(512, 4) void fused_iter(
        const unsigned short* __restrict__ Glo,
        const signed char* __restrict__ Ghi,
        float* __restrict__ pm) {
    __shared__ float wm[2][2][8];   // [buf][row][wave]
    __shared__ float ws[2][2][8];
    int t = threadIdx.x;
    int chunk = blockIdx.x;
    int i0 = chunk * RPB;
    int wave = t >> 6, lane = t & 63;

    float vreg[16];
    #pragma unroll
    for (int q = 0; q < 4; ++q) {
        f32x4 v = *(const f32x4*)&g_V[16 * t + 4 * q];
        vreg[4 * q + 0] = v.x; vreg[4 * q + 1] = v.y;
        vreg[4 * q + 2] = v.z; vreg[4 * q + 3] = v.w;
    }
    float cs[16];
    #pragma unroll
    for (int k = 0; k < 16; ++k) cs[k] = 0.0f;

    for (int w = 0; w < RPB / 2; ++w) {
        int buf = w & 1;
        int ra = i0 + 2 * w;
        int rb = ra + 1;
        float val0[16], val1[16];
        {
            const u16x8* lop = (const u16x8*)(Glo + (size_t)ra * B);
            const i8x16* hp  = (const i8x16*)(Ghi + (size_t)ra * B);
            u16x8 a0 = lop[2 * t], a1 = lop[2 * t + 1];
            i8x16 h = hp[t];
            #pragma unroll
            for (int e = 0; e < 8; ++e) {
                int q0 = ((int)h[e] << 16) | (int)a0[e];
                val0[e] = fmaf((float)q0, QI, vreg[e]);
                int q1 = ((int)h[8 + e] << 16) | (int)a1[e];
                val0[8 + e] = fmaf((float)q1, QI, vreg[8 + e]);
            }
        }
        {
            const u16x8* lop = (const u16x8*)(Glo + (size_t)rb * B);
            const i8x16* hp  = (const i8x16*)(Ghi + (size_t)rb * B);
            u16x8 a0 = lop[2 * t], a1 = lop[2 * t + 1];
            i8x16 h = hp[t];
            #pragma unroll
            for (int e = 0; e < 8; ++e) {
                int q0 = ((int)h[e] << 16) | (int)a0[e];
                val1[e] = fmaf((float)q0, QI, vreg[e]);
                int q1 = ((int)h[8 + e] << 16) | (int)a1[e];
                val1[8 + e] = fmaf((float)q1, QI, vreg[8 + e]);
            }
        }
        float M0 = val0[0], M1 = val1[0];
        #pragma unroll
        for (int k = 1; k < 16; ++k) {
            M0 = fmaxf(M0, val0[k]);
            M1 = fmaxf(M1, val1[k]);
        }
        #pragma unroll
        for (int off = 1; off < 64; off <<= 1) {
            M0 = fmaxf(M0, __shfl_xor(M0, off, 64));
            M1 = fmaxf(M1, __shfl_xor(M1, off, 64));
        }
        float s0 = 0.0f, s1 = 0.0f;
        #pragma unroll
        for (int k = 0; k < 16; ++k) {
            val0[k] = __expf(val0[k] - M0); s0 += val0[k];
            val1[k] = __expf(val1[k] - M1); s1 += val1[k];
        }
        #pragma unroll
        for (int off = 1; off < 64; off <<= 1) {
            s0 += __shfl_xor(s0, off, 64);
            s1 += __shfl_xor(s1, off, 64);
        }
        if (lane == 0) {
            wm[buf][0][wave] = M0; ws[buf][0][wave] = s0;
            wm[buf][1][wave] = M1; ws[buf][1][wave] = s1;
        }
        __syncthreads();
        float gM0 = wm[buf][0][0], gM1 = wm[buf][1][0];
        #pragma unroll
        for (int k = 1; k < 8; ++k) {
            gM0 = fmaxf(gM0, wm[buf][0][k]);
            gM1 = fmaxf(gM1, wm[buf][1][k]);
        }
        float gS0 = 0.0f, gS1 = 0.0f;
        #pragma unroll
        for (int k = 0; k < 8; ++k) {
            gS0 += ws[buf][0][k] * __expf(wm[buf][0][k] - gM0);
            gS1 += ws[buf][1][k] * __expf(wm[buf][1][k] - gM1);
        }
        float f0 = __expf(M0 - gM0) / gS0;
        float f1 = __expf(M1 - gM1) / gS1;
        #pragma unroll
        for (int k = 0; k < 16; ++k) {
            cs[k] = fmaf(val0[k], f0, cs[k]);
            cs[k] = fmaf(val1[k], f1, cs[k]);
        }
    }
    #pragma unroll
    for (int q = 0; q < 4; ++q) {
        f32x4 o = {cs[4 * q + 0], cs[4 * q + 1], cs[4 * q + 2], cs[4 * q + 3]};
        *(f32x4*)&pm[(size_t)chunk * B + 16 * t + 4 * q] = o;
    }
}

// ---------------- combine: V[j] -= log(sum of nch chunk partials) ----------------
// freeze0: if colsum is exactly 0 (sparse: no kept entries), leave V[j]
// unchanged instead of the +69 clamp push (prevents runaway; re-extract heals).
__global__ __launch_bounds__(256) void col_combine(const float* __restrict__ pm,
                                                   int nch, int freeze0) {
    int t = threadIdx.x;
    int pl = t & 31;
    int g = t >> 5;               // 0..7
    int j = blockIdx.x * 32 + pl;
    int per = nch >> 3;
    float s = 0.0f;
    for (int c = g * per; c < (g + 1) * per; ++c)
        s += pm[(size_t)c * B + j];
    __shared__ float ls[8][32];
    ls[g][pl] = s;
    __syncthreads();
    if (t < 32) {
        float s0 = ls[0][t];
        #pragma unroll
        for (int gg = 1; gg < 8; ++gg) s0 += ls[gg][t];
        int jj = blockIdx.x * 32 + t;
        if (!(freeze0 && s0 == 0.0f))
            g_V[jj] -= logf(fmaxf(s0, 1e-30f));
    }
}

// ---------------- extraction: per-row sparse candidate lists ----------------
// One wave per row (block = 8 waves). Pass 1: dense row LSE -> W.
// Pass 2 (with per-row tau tightening): keep val > W - tau, ballot-compact,
// write (j, int24 q) to sidx/svlo/svhi. g_cnt[row] = count.
__global__ __launch_bounds__(512, 2) void extract_sparse(
        const unsigned short* __restrict__ Glo,
        const signed char* __restrict__ Ghi,
        unsigned short* __restrict__ sidx,
        unsigned short* __restrict__ svlo,
        signed char* __restrict__ svhi) {
    __shared__ float V_lds[B];     // 32 KiB
    int t = threadIdx.x;
    int wave = t >> 6, lane = t & 63;
    #pragma unroll
    for (int k = 0; k < 4; ++k) {
        int fi = 2048 * k + 4 * t;
        *(f32x4*)&V_lds[fi] = *(const f32x4*)&g_V[fi];
    }
    __syncthreads();

    int row = blockIdx.x * 8 + wave;
    const u16x8* lop = (const u16x8*)(Glo + (size_t)row * B);
    const i8x8*  hp  = (const i8x8*)(Ghi + (size_t)row * B);

    // ---- pass 1: dense row LSE ----
    float m = -1e30f, s = 0.0f;
    for (int c = 0; c < 16; ++c) {
        int vi = c * 64 + lane;
        u16x8 lo = lop[vi];
        i8x8  hi = hp[vi];
        #pragma unroll
        for (int e = 0; e < 8; ++e) {
            int q = ((int)hi[e] << 16) | (int)lo[e];
            float val = fmaf((float)q, QI, V_lds[vi * 8 + e]);
            float d = val - m;
            float E = __expf(-fabsf(d));
            bool nm = d > 0.0f;
            s = nm ? fmaf(s, E, 1.0f) : (s + E);
            m = nm ? val : m;
        }
    }
    #pragma unroll
    for (int off = 1; off < 64; off <<= 1) {
        float mo = __shfl_xor(m, off, 64), so = __shfl_xor(s, off, 64);
        float m2 = fmaxf(m, mo);
        s = s * __expf(m - m2) + so * __expf(mo - m2);
        m = m2;
    }
    float W = m + logf(s);

    // ---- pass 2: filter + compact (tau tightens on overflow) ----
    unsigned long long lanelt = (1ULL << lane) - 1ULL;
    float tau = 80.0f;
    int cnt = 0;
    for (int attempt = 0; attempt < 5; ++attempt) {
        cnt = 0;
        float thresh = W - tau;
        for (int c = 0; c < 16; ++c) {
            int vi = c * 64 + lane;
            u16x8 lo = lop[vi];
            i8x8  hi = hp[vi];
            #pragma unroll
            for (int e = 0; e < 8; ++e) {
                int q = ((int)hi[e] << 16) | (int)lo[e];
                float val = fmaf((float)q, QI, V_lds[vi * 8 + e]);
                bool keep = val > thresh;
                unsigned long long mask = __ballot(keep);
                int pos = cnt + __popcll(mask & lanelt);
                if (keep && pos < KMAX) {
                    size_t o = (size_t)row * KMAX + pos;
                    sidx[o] = (unsigned short)(vi * 8 + e);
                    svlo[o] = (unsigned short)(q & 0xFFFF);
                    svhi[o] = (signed char)(q >> 16);
                }
                cnt += (int)__popcll(mask);
            }
        }
        if (cnt <= KMAX) break;
        tau -= 16.0f;
    }
    if (lane == 0) g_cnt[row] = (cnt < KMAX) ? cnt : KMAX;
}

// ---------------- sparse iteration ----------------
// 256 blocks x 512 thr; block owns SROWS=32 rows (wave handles 4, seq).
// Per row: pass1 LSE over kept entries -> W; pass2 P=exp(val-W) into LDS
// colsum (LDS atomics, ~10K adds/block). Writeout -> pm[chunk].
__global__ __launch_bounds__(512, 2) void sparse_iter(
        const unsigned short* __restrict__ sidx,
        const unsigned short* __restrict__ svlo,
        const signed char* __restrict__ svhi,
        float* __restrict__ pm) {
    __shared__ float V_lds[B];      // 32 KiB
    __shared__ float csum[B];       // 32 KiB
    int t = threadIdx.x;
    int wave = t >> 6, lane = t & 63;
    #pragma unroll
    for (int k = 0; k < 4; ++k) {
        int fi = 2048 * k + 4 * t;
        *(f32x4*)&V_lds[fi] = *(const f32x4*)&g_V[fi];
        *(f32x4*)&csum[fi] = f32x4{0.f, 0.f, 0.f, 0.f};
    }
    __syncthreads();

    int base = blockIdx.x * SROWS;
    for (int q = 0; q < 4; ++q) {
        int row = base + wave * 4 + q;
        int cnt = g_cnt[row];
        const unsigned short* sip = sidx + (size_t)row * KMAX;
        const unsigned short* slp = svlo + (size_t)row * KMAX;
        const signed char*    shp = svhi + (size_t)row * KMAX;
        // pass 1: LSE over kept entries
        float m = -1e30f, s = 0.0f;
        for (int e = lane; e < cnt; e += 64) {
            int qv = ((int)shp[e] << 16) | (int)slp[e];
            float val = fmaf((float)qv, QI, V_lds[sip[e]]);
            float d = val - m;
            float E = __expf(-fabsf(d));
            bool nm = d > 0.0f;
            s = nm ? fmaf(s, E, 1.0f) : (s + E);
            m = nm ? val : m;
        }
        #pragma unroll
        for (int off = 1; off < 64; off <<= 1) {
            float mo = __shfl_xor(m, off, 64), so = __shfl_xor(s, off, 64);
            float m2 = fmaxf(m, mo);
            s = s * __expf(m - m2) + so * __expf(mo - m2);
            m = m2;
        }
        float W = m + logf(s);
        // pass 2: scatter P into LDS colsum (reads are L1-hot)
        for (int e = lane; e < cnt; e += 64) {
            int j = sip[e];
            int qv = ((int)shp[e] << 16) | (int)slp[e];
            float val = fmaf((float)qv, QI, V_lds[j]);
            atomicAdd(&csum[j], __expf(val - W));
        }
    }
    __syncthreads();
    #pragma unroll
    for (int k = 0; k < 4; ++k) {
        int fi = 2048 * k + 4 * t;
        *(f32x4*)&pm[(size_t)blockIdx.x * B + fi] = *(const f32x4*)&csum[fi];
    }
}

// ---------------- argmax + gather: out[i] = y[argmax_j(G[i][j]+V[j])] ----------------
__global__ __launch_bounds__(256) void argmax_out(const unsigned short* __restrict__ Glo,
                                                  const signed char* __restrict__ Ghi,
                                                  const float* __restrict__ y,
                                                  float* __restrict__ out) {
    int i = blockIdx.x;
    int t = threadIdx.x;
    const u16x8* lo8 = (const u16x8*)(Glo + (size_t)i * B);
    const i8x8*  hi8 = (const i8x8*)(Ghi + (size_t)i * B);
    const f32x4* v4 = (const f32x4*)g_V;
    float best = -INFINITY;
    int bj = 0;
    #pragma unroll
    for (int it = 0; it < 4; ++it) {
        int idx = it * 256 + t;
        u16x8 lo = lo8[idx];
        i8x8  hi = hi8[idx];
        f32x4 va = v4[idx * 2], vb = v4[idx * 2 + 1];
        float vv[8] = {va.x, va.y, va.z, va.w, vb.x, vb.y, vb.z, vb.w};
        #pragma unroll
        for (int k = 0; k < 8; ++k) {
            int q = ((int)hi[k] << 16) | (int)lo[k];
            float val = fmaf((float)q, QI, vv[k]);
            int j = idx * 8 + k;
            if (val > best) { best = val; bj = j; }
        }
    }
    __shared__ float bm[256];
    __shared__ int   bidx[256];
    bm[t] = best; bidx[t] = bj;
    __syncthreads();
    #pragma unroll
    for (int off = 128; off; off >>= 1) {
        if (t < off) {
            float om = bm[t + off]; int oj = bidx[t + off];
            if (om > bm[t] || (om == bm[t] && oj < bidx[t])) { bm[t] = om; bidx[t] = oj; }
        }
        __syncthreads();
    }
    int jstar = bidx[0];
    out[(size_t)i * C + t] = y[(size_t)jstar * C + t];
}

extern "C" void kernel_launch(void* const* d_in, const int* in_sizes, int n_in,
                              void* d_out, int out_size, void* d_ws, size_t ws_size,
                              hipStream_t stream) {
    const float* x = (const float*)d_in[0];
    const float* y = (const float*)d_in[1];
    float* out = (float*)d_out;
    char* w = (char*)d_ws;
    unsigned short* Glo = (unsigned short*)w;                     // 128 MiB
    signed char*    Ghi = (signed char*)(w + (size_t)B * B * 2);  // +64 MiB
    float* pm = (float*)(w + (size_t)B * B * 3);                  // +16 MiB
    unsigned short* sidx = (unsigned short*)(w + (size_t)B * B * 3 + (size_t)NCH * B * 4);          // +16 MiB
    unsigned short* svlo = (unsigned short*)((char*)sidx + (size_t)B * KMAX * 2);                   // +16 MiB
    signed char*    svhi = (signed char*)((char*)svlo + (size_t)B * KMAX * 2);                      // +8 MiB

    init_V<<<B / 4, 256, 0, stream>>>(y);
    gemm_G<<<dim3(B / GT, B / GT), 256, 0, stream>>>(x, y, Glo, Ghi);

    // schedule: 8 dense | X | 24 sp | 1 dense | X | 23 sp | 1 dense | X |
    //           23 sp | 1 dense | X | 19 sp  = 100 iterations
    const int dense_runs[4]  = {8, 1, 1, 1};
    const int sparse_runs[4] = {24, 23, 23, 19};
    for (int ph = 0; ph < 4; ++ph) {
        for (int l = 0; l < dense_runs[ph]; ++l) {
            fused_iter<<<NCH, 512, 0, stream>>>(Glo, Ghi, pm);
            col_combine<<<B / 32, 256, 0, stream>>>(pm, NCH, 0);
        }
        extract_sparse<<<B / 8, 512, 0, stream>>>(Glo, Ghi, sidx, svlo, svhi);
        for (int l = 0; l < sparse_runs[ph]; ++l) {
            sparse_iter<<<SNCH, 512, 0, stream>>>(sidx, svlo, svhi, pm);
            col_combine<<<B / 32, 256, 0, stream>>>(pm, SNCH, 1);
        }
    }
    argmax_out<<<B, 256, 0, stream>>>(Glo, Ghi, y, out);
}

// Round 10
// 5485.669 us; speedup vs baseline: 1.2822x; 1.2822x over previous
//
#include <hip/hip_runtime.h>
#include <math.h>

// Sinkhorn OT layer, B=8192, C=256, L=100, LAMBD=1.
//
// U = log_u - ||x_i||^2, V = log_v - ||y_j||^2, G[i][j] = 2*dot(x_i,y_j):
//   U[i] = -LSE_j(G[i][j] + V[j]),  V[j] = -LSE_i(G[i][j] + U[i])
// init V[j] = -||y_j||^2. Final: out[i] = y[argmax_j(G[i][j]+V[j])].
//
// R6 int24 G: 7498. R11 register-resident fused iter: 4930. R13 one-barrier
// window: 4875 (~36 us fused_iter = AT the 224 MiB BW floor).
// R14 sparse (FAILED 7033): correct math, but LDS-atomic colsum + serial
// online-LSE made sparse iters slower than dense. Reverted.
// R15 = R13 + EXACT early termination. The V update is deterministic
// (fixed reduction orders, no atomics): V_{k+1} = F(V_k) bitwise. If
// V_{it+1} == V_{it-1} bitwise (2-slot history), the sequence is periodic
// with period 2 forever; V_100 = current V if (99-it) even, else one more
// iter. col_combine detects this (ballot-compare + last-block pattern)
// and sets g_done (with g_onemore for odd parity); subsequent dispatches
// early-return at entry (~2 us). If no bitwise cycle -> identical to R13.
// All state reset in init_V (graph-replay safe).
//
// Kept: int24 G (q=2^-15, err 1.5e-5), register-resident fusion (thread
// owns 16 cols, val[] survives the block row-reduce, 1 exp/element,
// G read once/iter), combine clamp, smallest-index argmax tie-break.

#define B 8192
#define C 256
#define LITERS 100
#define RPB 16                     // rows per fused block
#define NCH (B / RPB)              // 512 chunks

#define QS 65536.0f                // (2*acc) * 32768 == acc * 65536
#define QI 3.0517578125e-5f        // 2^-15

typedef float f32x4 __attribute__((ext_vector_type(4)));
typedef unsigned short u16x8 __attribute__((ext_vector_type(8)));
typedef signed char i8x16 __attribute__((ext_vector_type(16)));
typedef signed char i8x8 __attribute__((ext_vector_type(8)));

__device__ __align__(16) float g_V[B];
__device__ __align__(16) float g_Vhist[2][B];
__device__ int g_done, g_onemore, g_counter, g_eqblocks;

// ---------------- init: V[j] = -||y_j||^2, reset convergence state ----------------
__global__ __launch_bounds__(256) void init_V(const float* __restrict__ y) {
    int wave = threadIdx.x >> 6;
    int lane = threadIdx.x & 63;
    int row = blockIdx.x * 4 + wave;
    const f32x4* yr = (const f32x4*)(y + (size_t)row * C);
    f32x4 v = yr[lane];
    float s = v.x * v.x + v.y * v.y + v.z * v.z + v.w * v.w;
    #pragma unroll
    for (int off = 32; off; off >>= 1) s += __shfl_down(s, off, 64);
    if (lane == 0) g_V[row] = -s;
    if (blockIdx.x == 0) {
        float nanv = __uint_as_float(0x7FC00000u);   // never bit-matches real V
        for (int k = threadIdx.x; k < 2 * B; k += 256)
            ((float*)g_Vhist)[k] = nanv;
        if (threadIdx.x == 0) {
            g_done = 0; g_onemore = 0; g_counter = 0; g_eqblocks = 0;
        }
    }
}

// ---------------- GEMM: G = 2 * x @ y^T, quantized to int24 (R6 version) ----------------
#define GT 64
#define GKT 64
#define LSTR (GKT + 4)   // 68 floats; float4-aligned offsets

__global__ __launch_bounds__(256) void gemm_G(const float* __restrict__ x,
                                              const float* __restrict__ y,
                                              unsigned short* __restrict__ Glo,
                                              signed char* __restrict__ Ghi) {
    __shared__ float As[GT][LSTR];   // [i][k]
    __shared__ float Bs[GT][LSTR];   // [j][k]
    int bi = blockIdx.y * GT;
    int bj = blockIdx.x * GT;
    int t = threadIdx.x;
    int tx = t & 15, ty = t >> 4;
    float acc[4][4] = {};
    for (int kk = 0; kk < C; kk += GKT) {
        #pragma unroll
        for (int l = 0; l < 4; ++l) {
            int idx = t + l * 256;         // float4 index in tile
            int r = idx >> 4;              // tile row 0..63
            int c4 = idx & 15;             // float4 col 0..15
            *(f32x4*)&As[r][c4 * 4] =
                *(const f32x4*)(x + (size_t)(bi + r) * C + kk + c4 * 4);
            *(f32x4*)&Bs[r][c4 * 4] =
                *(const f32x4*)(y + (size_t)(bj + r) * C + kk + c4 * 4);
        }
        __syncthreads();
        #pragma unroll
        for (int k4 = 0; k4 < GKT / 4; ++k4) {
            f32x4 a[4], b[4];
            #pragma unroll
            for (int ii = 0; ii < 4; ++ii)
                a[ii] = *(const f32x4*)&As[ty * 4 + ii][k4 * 4];
            #pragma unroll
            for (int jj = 0; jj < 4; ++jj)
                b[jj] = *(const f32x4*)&Bs[tx + 16 * jj][k4 * 4];
            #pragma unroll
            for (int ii = 0; ii < 4; ++ii)
                #pragma unroll
                for (int jj = 0; jj < 4; ++jj) {
                    acc[ii][jj] = fmaf(a[ii].x, b[jj].x, acc[ii][jj]);
                    acc[ii][jj] = fmaf(a[ii].y, b[jj].y, acc[ii][jj]);
                    acc[ii][jj] = fmaf(a[ii].z, b[jj].z, acc[ii][jj]);
                    acc[ii][jj] = fmaf(a[ii].w, b[jj].w, acc[ii][jj]);
                }
        }
        __syncthreads();
    }
    #pragma unroll
    for (int ii = 0; ii < 4; ++ii) {
        int gi = bi + ty * 4 + ii;
        #pragma unroll
        for (int jj = 0; jj < 4; ++jj) {
            size_t idx = (size_t)gi * B + bj + tx + 16 * jj;
            float gs = acc[ii][jj] * QS;                       // G * 2^15
            gs = fminf(fmaxf(gs, -8388607.0f), 8388607.0f);    // int24 clamp
            int v = __float2int_rn(gs);
            Glo[idx] = (unsigned short)(v & 0xFFFF);
            Ghi[idx] = (signed char)(v >> 16);
        }
    }
}

// ---------------- fused row+col pass (R13, + g_done gate) ----------------
// Block = 512 threads (8 waves), owns rows [chunk*16, chunk*16+16).
// Thread t owns cols 16t..16t+15 for every row. Window = 2 rows.
__global__ __launch_bounds__(512, 4) void fused_iter(
        const unsigned short* __restrict__ Glo,
        const signed char* __restrict__ Ghi,
        float* __restrict__ pm) {
    if (g_done) return;
    __shared__ float wm[2][2][8];   // [buf][row][wave]
    __shared__ float ws[2][2][8];
    int t = threadIdx.x;
    int chunk = blockIdx.x;
    int i0 = chunk * RPB;
    int wave = t >> 6, lane = t & 63;

    float vreg[16];
    #pragma unroll
    for (int q = 0; q < 4; ++q) {
        f32x4 v = *(const f32x4*)&g_V[16 * t + 4 * q];
        vreg[4 * q + 0] = v.x; vreg[4 * q + 1] = v.y;
        vreg[4 * q + 2] = v.z; vreg[4 * q + 3] = v.w;
    }
    float cs[16];
    #pragma unroll
    for (int k = 0; k < 16; ++k) cs[k] = 0.0f;

    for (int w = 0; w < RPB / 2; ++w) {
        int buf = w & 1;
        int ra = i0 + 2 * w;
        int rb = ra + 1;
        float val0[16], val1[16];
        {
            const u16x8* lop = (const u16x8*)(Glo + (size_t)ra * B);
            const i8x16* hp  = (const i8x16*)(Ghi + (size_t)ra * B);
            u16x8 a0 = lop[2 * t], a1 = lop[2 * t + 1];
            i8x16 h = hp[t];
            #pragma unroll
            for (int e = 0; e < 8; ++e) {
                int q0 = ((int)h[e] << 16) | (int)a0[e];
                val0[e] = fmaf((float)q0, QI, vreg[e]);
                int q1 = ((int)h[8 + e] << 16) | (int)a1[e];
                val0[8 + e] = fmaf((float)q1, QI, vreg[8 + e]);
            }
        }
        {
            const u16x8* lop = (const u16x8*)(Glo + (size_t)rb * B);
            const i8x16* hp  = (const i8x16*)(Ghi + (size_t)rb * B);
            u16x8 a0 = lop[2 * t], a1 = lop[2 * t + 1];
            i8x16 h = hp[t];
            #pragma unroll
            for (int e = 0; e < 8; ++e) {
                int q0 = ((int)h[e] << 16) | (int)a0[e];
                val1[e] = fmaf((float)q0, QI, vreg[e]);
                int q1 = ((int)h[8 + e] << 16) | (int)a1[e];
                val1[8 + e] = fmaf((float)q1, QI, vreg[8 + e]);
            }
        }
        float M0 = val0[0], M1 = val1[0];
        #pragma unroll
        for (int k = 1; k < 16; ++k) {
            M0 = fmaxf(M0, val0[k]);
            M1 = fmaxf(M1, val1[k]);
        }
        #pragma unroll
        for (int off = 1; off < 64; off <<= 1) {
            M0 = fmaxf(M0, __shfl_xor(M0, off, 64));
            M1 = fmaxf(M1, __shfl_xor(M1, off, 64));
        }
        float s0 = 0.0f, s1 = 0.0f;
        #pragma unroll
        for (int k = 0; k < 16; ++k) {
            val0[k] = __expf(val0[k] - M0); s0 += val0[k];
            val1[k] = __expf(val1[k] - M1); s1 += val1[k];
        }
        #pragma unroll
        for (int off = 1; off < 64; off <<= 1) {
            s0 += __shfl_xor(s0, off, 64);
            s1 += __shfl_xor(s1, off, 64);
        }
        if (lane == 0) {
            wm[buf][0][wave] = M0; ws[buf][0][wave] = s0;
            wm[buf][1][wave] = M1; ws[buf][1][wave] = s1;
        }
        __syncthreads();
        float gM0 = wm[buf][0][0], gM1 = wm[buf][1][0];
        #pragma unroll
        for (int k = 1; k < 8; ++k) {
            gM0 = fmaxf(gM0, wm[buf][0][k]);
            gM1 = fmaxf(gM1, wm[buf][1][k]);
        }
        float gS0 = 0.0f, gS1 = 0.0f;
        #pragma unroll
        for (int k = 0; k < 8; ++k) {
            gS0 += ws[buf][0][k] * __expf(wm[buf][0][k] - gM0);
            gS1 += ws[buf][1][k] * __expf(wm[buf][1][k] - gM1);
        }
        float f0 = __expf(M0 - gM0) / gS0;
        float f1 = __expf(M1 - gM1) / gS1;
        #pragma unroll
        for (int k = 0; k < 16; ++k) {
            cs[k] = fmaf(val0[k], f0, cs[k]);
            cs[k] = fmaf(val1[k], f1, cs[k]);
        }
    }
    #pragma unroll
    for (int q = 0; q < 4; ++q) {
        f32x4 o = {cs[4 * q + 0], cs[4 * q + 1], cs[4 * q + 2], cs[4 * q + 3]};
        *(f32x4*)&pm[(size_t)chunk * B + 16 * t + 4 * q] = o;
    }
}

// ---------------- combine: V[j] -= log(colsum); detect bitwise 2-cycle ----------------
__global__ __launch_bounds__(256) void col_combine(const float* __restrict__ pm,
                                                   int it) {
    if (g_done) return;
    int t = threadIdx.x;
    int pl = t & 31;
    int g = t >> 5;               // 0..7
    int j = blockIdx.x * 32 + pl;
    float s = 0.0f;
    #pragma unroll 8
    for (int c = g * 64; c < g * 64 + 64; ++c)
        s += pm[(size_t)c * B + j];
    __shared__ float ls[8][32];
    ls[g][pl] = s;
    __syncthreads();
    if (t < 32) {
        float s0 = ls[0][t];
        #pragma unroll
        for (int gg = 1; gg < 8; ++gg) s0 += ls[gg][t];
        int jj = blockIdx.x * 32 + t;
        // clamp: all-underflow columns get a bounded push (self-correcting)
        float vnew = g_V[jj] - logf(fmaxf(s0, 1e-30f));
        g_V[jj] = vnew;
        // bitwise compare vs V from two iterations ago; update history
        unsigned bnew = __float_as_uint(vnew);
        unsigned bold = __float_as_uint(g_Vhist[it & 1][jj]);
        g_Vhist[it & 1][jj] = vnew;
        unsigned long long m = __ballot(bnew == bold);   // lanes 0..31 active
        if (t == 0 && m == 0xFFFFFFFFull)
            atomicAdd(&g_eqblocks, 1);
    }
    if (t == 0) {
        __threadfence();
        int prev = atomicAdd(&g_counter, 1);
        if (prev == (int)gridDim.x - 1) {         // last block to finish
            __threadfence();
            int eqb = atomicAdd(&g_eqblocks, 0);  // atomic read
            g_counter = 0;
            g_eqblocks = 0;
            if (g_onemore) {                      // parity iter completed
                g_done = 1; g_onemore = 0;
            } else if (eqb == (int)gridDim.x) {
                // V_{it+1} == V_{it-1} bitwise => period-2 forever.
                // V_100 = V_{it+1} iff (99-it) even; else one more iter.
                int R = (LITERS - 1) - it;
                if (R & 1) g_onemore = 1;
                else       g_done = 1;
            }
            __threadfence();
        }
    }
}

// ---------------- argmax + gather: out[i] = y[argmax_j(G[i][j]+V[j])] ----------------
__global__ __launch_bounds__(256) void argmax_out(const unsigned short* __restrict__ Glo,
                                                  const signed char* __restrict__ Ghi,
                                                  const float* __restrict__ y,
                                                  float* __restrict__ out) {
    int i = blockIdx.x;
    int t = threadIdx.x;
    const u16x8* lo8 = (const u16x8*)(Glo + (size_t)i * B);
    const i8x8*  hi8 = (const i8x8*)(Ghi + (size_t)i * B);
    const f32x4* v4 = (const f32x4*)g_V;
    float best = -INFINITY;
    int bj = 0;                              // safe init (never OOB)
    #pragma unroll
    for (int it = 0; it < 4; ++it) {
        int idx = it * 256 + t;
        u16x8 lo = lo8[idx];
        i8x8  hi = hi8[idx];
        f32x4 va = v4[idx * 2], vb = v4[idx * 2 + 1];
        float vv[8] = {va.x, va.y, va.z, va.w, vb.x, vb.y, vb.z, vb.w};
        #pragma unroll
        for (int k = 0; k < 8; ++k) {
            int q = ((int)hi[k] << 16) | (int)lo[k];
            float val = fmaf((float)q, QI, vv[k]);
            int j = idx * 8 + k;
            if (val > best) { best = val; bj = j; }
        }
    }
    __shared__ float bm[256];
    __shared__ int   bidx[256];
    bm[t] = best; bidx[t] = bj;
    __syncthreads();
    #pragma unroll
    for (int off = 128; off; off >>= 1) {
        if (t < off) {
            float om = bm[t + off]; int oj = bidx[t + off];
            if (om > bm[t] || (om == bm[t] && oj < bidx[t])) { bm[t] = om; bidx[t] = oj; }
        }
        __syncthreads();
    }
    int jstar = bidx[0];
    out[(size_t)i * C + t] = y[(size_t)jstar * C + t];
}

extern "C" void kernel_launch(void* const* d_in, const int* in_sizes, int n_in,
                              void* d_out, int out_size, void* d_ws, size_t ws_size,
                              hipStream_t stream) {
    const float* x = (const float*)d_in[0];
    const float* y = (const float*)d_in[1];
    float* out = (float*)d_out;
    unsigned short* Glo = (unsigned short*)d_ws;                           // 128 MiB
    signed char*    Ghi = (signed char*)((char*)d_ws + (size_t)B * B * 2); // +64 MiB
    float* pm = (float*)((char*)d_ws + (size_t)B * B * 3);                 // +16 MiB

    init_V<<<B / 4, 256, 0, stream>>>(y);
    gemm_G<<<dim3(B / GT, B / GT), 256, 0, stream>>>(x, y, Glo, Ghi);
    for (int l = 0; l < LITERS; ++l) {
        fused_iter<<<NCH, 512, 0, stream>>>(Glo, Ghi, pm);
        col_combine<<<B / 32, 256, 0, stream>>>(pm, l);
    }
    argmax_out<<<B, 256, 0, stream>>>(Glo, Ghi, y, out);
}